// Round 5
// baseline (4647.102 us; speedup 1.0000x reference)
//
#include <hip/hip_runtime.h>
#include <math.h>

typedef float v4 __attribute__((ext_vector_type(4)));
typedef unsigned long long u64;

static constexpr int B_ = 32;
static constexpr int S_ = 2048;
static constexpr int E_ = 512;
static constexpr int V_ = 32000;
static constexpr float EPS_ = 1e-6f;
static constexpr int NH_ = 8;     // blocks (column slices) per batch
static constexpr int CH_ = 64;    // columns per block

// ---------------------------------------------------------------------------
// K1: 8-blocks-per-batch scan, 256 blocks x 1024 threads (1 block/CU).
// Protocol: per-element TAGGED u64 (tag<<32 | value bits), parity dbuf.
//   publish: RELAXED AGENT atomic 8B stores (formal atomicity, tag travels
//            WITH data -> no ordering assumption, replay-safe via memset).
//   gather (NEW): wide plain `global_load_dwordx4 sc0 sc1` — same cache
//            semantics as an agent atomic load (bypass L1 + non-coherent
//            local L2, read coherence point) but COALESCED: one wave per
//            foreign slice reads all 64 tagged words (512B) in 4 fabric
//            transactions per spin iteration (vs 64 separate atomics).
//            Tags checked per element; any stale -> re-read slice.
//   This attacks the measured bottleneck: ~4000 cy/step of exchange wait
//   dominated by the queueing TAIL of ~500K uncoalesced 8B atomic polls
//   per step chip-wide (round-4 post-mortem).
// Waves: 0 = col-reduce+publish+stats, 8 = stats gather, 9..15 = value
// gather (one foreign slice each), 1..7 idle to B2. 3 barriers/step.
// ---------------------------------------------------------------------------
__global__ __launch_bounds__(1024) void scan8w(
    const int* __restrict__ seq,     // (B,S)
    const float* __restrict__ emb,   // (V,E)
    const float* __restrict__ Wdec,  // (E,E) row-major
    const float* __restrict__ bdec,  // (E)
    const float* __restrict__ gamma, // (E)
    const float* __restrict__ beta,  // (E)
    float* __restrict__ zout,        // (B,E)
    u64* __restrict__ zpub)          // values (B,2,E) + stats (B,2,2,8)
{
    __shared__ __align__(16) float zs[E_];        // z_in
    __shared__ __align__(16) float part[16][CH_]; // matvec partials
    __shared__ __align__(16) float zmbuf[E_];     // gathered zmid (all 512)
    __shared__ float sst[NH_][2];                 // per-slice (S,Q)
    __shared__ int   seq_l[S_];

    const int bid  = blockIdx.x;
    const int b    = bid & 31;    // batch
    const int h    = bid >> 5;    // slice 0..7
    const int c0   = h * CH_;
    const int tid  = threadIdx.x;
    const int wv   = tid >> 6;    // 16 waves
    const int lane = tid & 63;
    const int cg   = lane & 15;   // 4-col group
    const int sub  = lane >> 4;   // 8-row subchunk
    const int row0 = wv * 32 + sub * 8;

    // --- W slice into VGPRs (8 x v4 = 32 regs), pinned via asm ---
    v4 w[8];
    {
        const float* wp = Wdec + (size_t)row0 * E_ + c0 + 4 * cg;
        #pragma unroll
        for (int q = 0; q < 8; ++q) {
            const float* p = wp + (size_t)q * E_;
            asm volatile("global_load_dwordx4 %0, %1, off\n\ts_waitcnt vmcnt(0)"
                         : "=v"(w[q]) : "v"(p));
        }
    }

    const int* seqb = seq + (size_t)b * S_;
    for (int i = tid; i < S_; i += 1024) seq_l[i] = seqb[i];

    const float gmm = (tid < E_) ? gamma[tid] : 0.f;
    const float btt = (tid < E_) ? beta[tid] : 0.f;
    const float bdr = (tid < CH_) ? bdec[c0 + tid] : 0.f;
    const float sqrtE = sqrtf(512.0f);
    u64* zpb = zpub + (size_t)b * 2 * E_;                     // values
    u64* zst = zpub + (size_t)B_ * 2 * E_ + (size_t)b * 32;   // [p][k][8]

    // value-gather wave setup: wave 9+j handles foreign slice fs
    int fs = 0;
    if (wv >= 9) { const int j = wv - 9; fs = j + ((j >= h) ? 1 : 0); }

    __syncthreads();
    if (tid < E_) zs[tid] = emb[(size_t)seq_l[0] * E_ + tid] * sqrtE;  // x_0
    __syncthreads();

    for (int t = 0; t < S_; ++t) {
        const int p = t & 1;
        const unsigned tag = (unsigned)(t + 1);

        // prefetch next embedding row (consumed at step end)
        const int tn = seq_l[(t + 1 < S_) ? t + 1 : t];
        float e = 0.f;
        if (tid < E_) e = emb[(size_t)tn * E_ + tid];

        // --- matvec: 8 rows x own 4 cols per thread (proven mapping) ---
        const v4 za = *(const v4*)&zs[row0];
        const v4 zb = *(const v4*)&zs[row0 + 4];
        v4 acc = za.x * w[0];
        acc += za.y * w[1];
        acc += za.z * w[2];
        acc += za.w * w[3];
        acc += zb.x * w[4];
        acc += zb.y * w[5];
        acc += zb.z * w[6];
        acc += zb.w * w[7];
        // reduce over sub (lanes cg, cg+16, cg+32, cg+48)
        acc.x += __shfl_down(acc.x, 16);
        acc.y += __shfl_down(acc.y, 16);
        acc.z += __shfl_down(acc.z, 16);
        acc.w += __shfl_down(acc.w, 16);
        acc.x += __shfl_down(acc.x, 32);
        acc.y += __shfl_down(acc.y, 32);
        acc.z += __shfl_down(acc.z, 32);
        acc.w += __shfl_down(acc.w, 32);
        if (lane < 16) *(v4*)&part[wv][4 * cg] = acc;
        __syncthreads();                                   // B1

        if (tid < CH_) {
            // --- wave 0: col-reduce, publish values (atomic), then stats ---
            float sum = part[0][tid];
            #pragma unroll
            for (int k = 1; k < 16; ++k) sum += part[k][tid];
            const float zmid = zs[c0 + tid] + sum + bdr;
            union { float f; unsigned u; } cv; cv.f = zmid;
            __hip_atomic_store(&zpb[p * E_ + c0 + tid],
                               ((u64)tag << 32) | cv.u,
                               __ATOMIC_RELAXED, __HIP_MEMORY_SCOPE_AGENT);
            zmbuf[c0 + tid] = zmid;            // own slice -> LDS
            // slice stats butterfly (overlaps value-store flight)
            float s = zmid, q2 = zmid * zmid;
            #pragma unroll
            for (int m = 1; m < 64; m <<= 1) {
                s  += __shfl_xor(s, m);
                q2 += __shfl_xor(q2, m);
            }
            if (tid == 0) {
                union { float f; unsigned u; } c1, c2; c1.f = s; c2.f = q2;
                __hip_atomic_store(&zst[p * 16 + 0 + h], ((u64)tag << 32) | c1.u,
                                   __ATOMIC_RELAXED, __HIP_MEMORY_SCOPE_AGENT);
                __hip_atomic_store(&zst[p * 16 + 8 + h], ((u64)tag << 32) | c2.u,
                                   __ATOMIC_RELAXED, __HIP_MEMORY_SCOPE_AGENT);
                sst[h][0] = s; sst[h][1] = q2;
            }
        } else if (wv == 8) {
            // --- stats gather: lanes 0..7 wide-load 2 tagged words each ---
            const bool need = (lane < 8);
            const int l2 = 2 * (lane & 7);
            const u64* ap = &zst[p * 16 + l2];
            const int i0 = l2 & 7,       k0 = l2 >> 3;
            const int i1 = (l2 + 1) & 7, k1 = (l2 + 1) >> 3;
            v4 r = {0.f, 0.f, 0.f, 0.f};
            for (;;) {
                if (need)
                    asm volatile(
                        "global_load_dwordx4 %0, %1, off sc0 sc1\n\t"
                        "s_waitcnt vmcnt(0)"
                        : "=v"(r) : "v"(ap) : "memory");
                bool ok = true;
                if (need)
                    ok = ((i0 == h) || (__float_as_uint(r.y) == tag))
                      && ((i1 == h) || (__float_as_uint(r.w) == tag));
                if (__all(ok)) break;
            }
            if (need) {
                if (i0 != h) sst[i0][k0] = r.x;
                if (i1 != h) sst[i1][k1] = r.z;
            }
        } else if (wv >= 9) {
            // --- value gather: 32 lanes x dwordx4 = whole foreign slice ---
            const bool need = (lane < 32);
            const u64* ap = &zpb[p * E_ + fs * CH_ + 2 * (lane & 31)];
            v4 r = {0.f, 0.f, 0.f, 0.f};
            for (;;) {
                if (need)
                    asm volatile(
                        "global_load_dwordx4 %0, %1, off sc0 sc1\n\t"
                        "s_waitcnt vmcnt(0)"
                        : "=v"(r) : "v"(ap) : "memory");
                bool ok = true;
                if (need)
                    ok = (__float_as_uint(r.y) == tag)
                      && (__float_as_uint(r.w) == tag);
                if (__all(ok)) break;
            }
            if (need) {
                zmbuf[fs * CH_ + 2 * lane]     = r.x;
                zmbuf[fs * CH_ + 2 * lane + 1] = r.z;
            }
        }
        __syncthreads();                                   // B2

        if (tid < E_) {
            // LN from broadcast LDS stats (fixed order -> identical in all
            // 8 replica blocks of this batch)
            const float St =
                ((sst[0][0] + sst[1][0]) + (sst[2][0] + sst[3][0]))
              + ((sst[4][0] + sst[5][0]) + (sst[6][0] + sst[7][0]));
            const float Qt =
                ((sst[0][1] + sst[1][1]) + (sst[2][1] + sst[3][1]))
              + ((sst[4][1] + sst[5][1]) + (sst[6][1] + sst[7][1]));
            const float mu   = St * (1.0f / E_);
            const float var  = (Qt - St * mu) * (1.0f / (E_ - 1));
            const float invd = 1.0f / (sqrtf(var) + EPS_);
            const float zl   = gmm * (zmbuf[tid] - mu) * invd + btt;
            if (t == S_ - 1) {
                if (h == 0) zout[(size_t)b * E_ + tid] = zl;
            } else {
                zs[tid] = fmaf(e, sqrtE, zl);
            }
        }
        __syncthreads();                                   // B3
    }
}

// ---------------------------------------------------------------------------
// K2: y = z @ W_voc + b_voc. 250 blocks x 512 threads; each thread owns one
// vocab column for 8 batches (bg group). z reads are thread-uniform ->
// scalar-cache loads; W_voc streamed once (same cols across bg reuse L1).
// ---------------------------------------------------------------------------
__global__ __launch_bounds__(512) void logits_k(
    const float* __restrict__ zfin,  // (B,E)
    const float* __restrict__ Wvoc,  // (E,V)
    const float* __restrict__ bvoc,  // (V)
    float* __restrict__ y)           // (B,V)
{
    const int tid = threadIdx.x;
    const int col = blockIdx.x * 128 + (tid & 127);
    const int bg  = (tid >> 7) * 8;           // 0,8,16,24

    float acc[8] = {0.f, 0.f, 0.f, 0.f, 0.f, 0.f, 0.f, 0.f};
    const float* wp = Wvoc + col;
    const float* zp = zfin + (size_t)bg * E_;

    for (int k = 0; k < E_; k += 4) {
        const float w0 = wp[(size_t)(k + 0) * V_];
        const float w1 = wp[(size_t)(k + 1) * V_];
        const float w2 = wp[(size_t)(k + 2) * V_];
        const float w3 = wp[(size_t)(k + 3) * V_];
        #pragma unroll
        for (int g = 0; g < 8; ++g) {
            acc[g] = fmaf(zp[g * E_ + k + 0], w0, acc[g]);
            acc[g] = fmaf(zp[g * E_ + k + 1], w1, acc[g]);
            acc[g] = fmaf(zp[g * E_ + k + 2], w2, acc[g]);
            acc[g] = fmaf(zp[g * E_ + k + 3], w3, acc[g]);
        }
    }
    const float bv = bvoc[col];
    #pragma unroll
    for (int g = 0; g < 8; ++g)
        y[(size_t)(bg + g) * V_ + col] = acc[g] + bv;
}

// ---------------------------------------------------------------------------
// K3: per-batch log-sum-exp (bias already folded into y)
// ---------------------------------------------------------------------------
__global__ __launch_bounds__(1024) void lse_k(
    const float* __restrict__ y, float* __restrict__ corr)
{
    __shared__ float redm[16], redl[16];
    const int b = blockIdx.x;
    const int tid = threadIdx.x;
    const float* row = y + (size_t)b * V_;

    float m = -3.0e38f, l = 0.f;
    for (int v = tid; v < V_; v += 1024) {
        const float x = row[v];
        const float nm = fmaxf(m, x);
        l = l * __expf(m - nm) + __expf(x - nm);
        m = nm;
    }
    #pragma unroll
    for (int off = 32; off > 0; off >>= 1) {
        const float om = __shfl_down(m, off);
        const float ol = __shfl_down(l, off);
        const float nm = fmaxf(m, om);
        l = l * __expf(m - nm) + ol * __expf(om - nm);
        m = nm;
    }
    const int lane = tid & 63, wvv = tid >> 6;
    if (lane == 0) { redm[wvv] = m; redl[wvv] = l; }
    __syncthreads();
    if (tid == 0) {
        float M = redm[0], L = redl[0];
        for (int k = 1; k < 16; ++k) {
            const float nm = fmaxf(M, redm[k]);
            L = L * __expf(M - nm) + redl[k] * __expf(redm[k] - nm);
            M = nm;
        }
        corr[b] = M + logf(L);
    }
}

// ---------------------------------------------------------------------------
// K4: y -= corr[b]
// ---------------------------------------------------------------------------
__global__ __launch_bounds__(256) void fix_k(
    float* __restrict__ y, const float* __restrict__ corr)
{
    const int idx = blockIdx.x * 256 + threadIdx.x;   // float4 index
    const size_t o = (size_t)idx * 4;
    const int b = (int)(o / V_);
    const float cr = corr[b];
    v4 v = *(v4*)(y + o);
    v = v - cr;
    *(v4*)(y + o) = v;
}

// ---------------------------------------------------------------------------
extern "C" void kernel_launch(void* const* d_in, const int* in_sizes, int n_in,
                              void* d_out, int out_size, void* d_ws, size_t ws_size,
                              hipStream_t stream)
{
    (void)in_sizes; (void)n_in; (void)out_size; (void)ws_size;
    // 0=hidden_state (unused), 1=output_sequence, 2=emb_out, 3=W_dec,
    // 4=b_dec, 5=gamma, 6=beta, 7=W_voc, 8=b_voc
    const int*   seq  = (const int*)  d_in[1];
    const float* emb  = (const float*)d_in[2];
    const float* Wdec = (const float*)d_in[3];
    const float* bdec = (const float*)d_in[4];
    const float* gam  = (const float*)d_in[5];
    const float* bet  = (const float*)d_in[6];
    const float* Wvoc = (const float*)d_in[7];
    const float* bvoc = (const float*)d_in[8];

    float* out  = (float*)d_out;
    float* zout = out;            // B*E floats
    float* y    = out + B_ * E_;  // B*V floats

    // workspace: values (B*2*E u64) + stats (B*2*2*8 u64) + corr
    const size_t exch_u64 = (size_t)B_ * 2 * E_ + (size_t)B_ * 32;
    u64*   zpub = (u64*)d_ws;
    float* corr = (float*)((char*)d_ws + exch_u64 * sizeof(u64)); // B floats

    // tags must not alias t+1 from a previous replay — zero the exchange buf
    hipMemsetAsync(zpub, 0, exch_u64 * sizeof(u64), stream);

    hipLaunchKernelGGL(scan8w, dim3(B_ * NH_), dim3(1024), 0, stream,
                       seq, emb, Wdec, bdec, gam, bet, zout, zpub);
    hipLaunchKernelGGL(logits_k, dim3(V_ / 128), dim3(512), 0, stream,
                       zout, Wvoc, bvoc, y);
    hipLaunchKernelGGL(lse_k, dim3(B_), dim3(1024), 0, stream, y, corr);
    hipLaunchKernelGGL(fix_k, dim3(1000), dim3(256), 0, stream, y, corr);
}

// Round 6
// 4137.849 us; speedup vs baseline: 1.1231x; 1.1231x over previous
//
#include <hip/hip_runtime.h>
#include <math.h>

typedef float v4 __attribute__((ext_vector_type(4)));
typedef unsigned long long u64;

static constexpr int B_ = 32;
static constexpr int S_ = 2048;
static constexpr int E_ = 512;
static constexpr int V_ = 32000;
static constexpr float EPS_ = 1e-6f;
static constexpr int NH_ = 8;     // blocks (column slices) per batch
static constexpr int CH_ = 64;    // columns per block

// ---------------------------------------------------------------------------
// K1: 8-blocks-per-batch scan, 256 blocks x 1024 threads (1 block/CU).
// TWO barriers per step (was 4 in round-0):
//  * wave w (of 8 compute waves) owns z rows [64w,64w+64): it writes them in
//    the LN and is the ONLY reader in the matvec -> zs-write->matvec is an
//    intra-wave LDS RAW (lgkmcnt-ordered), no barrier needed.
//  * LN stats (S,Q) are computed REDUNDANTLY per wave from the gathered
//    zmbuf in a fixed order (identical bits in all 8 replica blocks) ->
//    no stats exchange, no stats barrier.
// Exchange protocol: round-0 proven per-element TAGGED u64 relaxed agent
// atomics (no cache-maintenance ops, self-validating, replay-safe), now
// polled with a compiler-managed 2-deep pipelined load pair (vmcnt(1)
// waits -> discovery granularity ~RT/2).
// Deadlock-free: publishes depend only on B1; polls cannot block publishes;
// max inter-block skew is one publish (opposite parity slot).
// ---------------------------------------------------------------------------
__global__ __launch_bounds__(1024) void scan2b(
    const int* __restrict__ seq,     // (B,S)
    const float* __restrict__ emb,   // (V,E)
    const float* __restrict__ Wdec,  // (E,E) row-major
    const float* __restrict__ bdec,  // (E)
    const float* __restrict__ gamma, // (E)
    const float* __restrict__ beta,  // (E)
    float* __restrict__ zout,        // (B,E)
    u64* __restrict__ zpub)          // values (B,2,E) tagged exchange
{
    __shared__ __align__(16) float zs[E_];        // z_in
    __shared__ __align__(16) float part[NH_][CH_];// matvec partials (8/col)
    __shared__ __align__(16) float zmbuf[E_];     // gathered zmid (all 512)
    __shared__ int   seq_l[S_];

    const int bid  = blockIdx.x;
    const int b    = bid & 31;    // batch
    const int h    = bid >> 5;    // slice 0..7
    const int c0   = h * CH_;
    const int tid  = threadIdx.x;
    const int wv   = tid >> 6;    // 16 waves
    const int lane = tid & 63;
    const int cg   = lane & 15;   // 4-col group
    const int sub  = lane >> 4;   // 16-row subchunk
    const bool comp = (wv < 8);   // waves 0..7 compute, 8..14 poll, 15 idle
    const int row0 = wv * 64 + sub * 16;

    // --- W slice: thread holds W[row0+q][c0+4cg..+3], q=0..15 (64 VGPRs,
    //     asm-pinned exactly like the proven round-0 pattern, 2x deeper) ---
    v4 w[16];
    if (comp) {
        const float* wp = Wdec + (size_t)row0 * E_ + c0 + 4 * cg;
        #pragma unroll
        for (int q = 0; q < 16; ++q) {
            const float* p = wp + (size_t)q * E_;
            asm volatile("global_load_dwordx4 %0, %1, off\n\ts_waitcnt vmcnt(0)"
                         : "=v"(w[q]) : "v"(p));
        }
    }

    const int* seqb = seq + (size_t)b * S_;
    for (int i = tid; i < S_; i += 1024) seq_l[i] = seqb[i];

    const float gmm = (tid < E_) ? gamma[tid] : 0.f;
    const float btt = (tid < E_) ? beta[tid] : 0.f;
    const float bdr = (tid < CH_) ? bdec[c0 + tid] : 0.f;
    const float sqrtE = sqrtf(512.0f);
    u64* zpb = zpub + (size_t)b * 2 * E_;

    // poller wave setup: wave 8+j handles foreign slice fs, one elem/lane
    int fs = 0;
    if (wv >= 8 && wv < 15) { const int j = wv - 8; fs = j + ((j >= h) ? 1 : 0); }

    __syncthreads();
    if (tid < E_) zs[tid] = emb[(size_t)seq_l[0] * E_ + tid] * sqrtE;  // x_0
    __syncthreads();

    for (int t = 0; t < S_; ++t) {
        const int p = t & 1;
        const unsigned tag = (unsigned)(t + 1);

        float e = 0.f;
        if (comp) {
            // prefetch next embedding row (consumed at step end)
            const int tn = seq_l[(t + 1 < S_) ? t + 1 : t];
            e = emb[(size_t)tn * E_ + tid];

            // --- matvec: 16 own-wave rows x own 4 cols (intra-wave RAW
            //     with the zs write below; compiler inserts lgkmcnt) ---
            const v4 za = *(const v4*)&zs[row0];
            const v4 zb = *(const v4*)&zs[row0 + 4];
            const v4 zc = *(const v4*)&zs[row0 + 8];
            const v4 zd = *(const v4*)&zs[row0 + 12];
            v4 acc = za.x * w[0];
            acc += za.y * w[1];
            acc += za.z * w[2];
            acc += za.w * w[3];
            acc += zb.x * w[4];
            acc += zb.y * w[5];
            acc += zb.z * w[6];
            acc += zb.w * w[7];
            acc += zc.x * w[8];
            acc += zc.y * w[9];
            acc += zc.z * w[10];
            acc += zc.w * w[11];
            acc += zd.x * w[12];
            acc += zd.y * w[13];
            acc += zd.z * w[14];
            acc += zd.w * w[15];
            // reduce over sub (lanes cg, cg+16, cg+32, cg+48)
            acc.x += __shfl_down(acc.x, 16);
            acc.y += __shfl_down(acc.y, 16);
            acc.z += __shfl_down(acc.z, 16);
            acc.w += __shfl_down(acc.w, 16);
            acc.x += __shfl_down(acc.x, 32);
            acc.y += __shfl_down(acc.y, 32);
            acc.z += __shfl_down(acc.z, 32);
            acc.w += __shfl_down(acc.w, 32);
            if (lane < 16) *(v4*)&part[wv][4 * cg] = acc;
        }
        __syncthreads();                                   // B1

        if (tid < CH_) {
            // --- wave 0: col-reduce (8 terms), publish own slice ---
            const float sum = ((part[0][tid] + part[1][tid])
                             + (part[2][tid] + part[3][tid]))
                            + ((part[4][tid] + part[5][tid])
                             + (part[6][tid] + part[7][tid]));
            const float zmid = zs[c0 + tid] + sum + bdr;
            union { float f; unsigned u; } cv; cv.f = zmid;
            __hip_atomic_store(&zpb[p * E_ + c0 + tid],
                               ((u64)tag << 32) | cv.u,
                               __ATOMIC_RELAXED, __HIP_MEMORY_SCOPE_AGENT);
            zmbuf[c0 + tid] = zmid;            // own slice -> LDS
        } else if (wv >= 8 && wv < 15) {
            // --- 2-deep pipelined tagged poll (compiler-managed vmcnt) ---
            const u64* ap = &zpb[p * E_ + fs * CH_ + lane];
            u64 s0 = __hip_atomic_load(ap, __ATOMIC_RELAXED,
                                       __HIP_MEMORY_SCOPE_AGENT);
            u64 s1 = __hip_atomic_load(ap, __ATOMIC_RELAXED,
                                       __HIP_MEMORY_SCOPE_AGENT);
            float val = 0.f;
            bool done = false;
            for (;;) {
                if (!done && (unsigned)(s0 >> 32) == tag) {
                    val = __uint_as_float((unsigned)s0); done = true;
                }
                if (__all(done)) break;
                s0 = __hip_atomic_load(ap, __ATOMIC_RELAXED,
                                       __HIP_MEMORY_SCOPE_AGENT);
                if (!done && (unsigned)(s1 >> 32) == tag) {
                    val = __uint_as_float((unsigned)s1); done = true;
                }
                if (__all(done)) break;
                s1 = __hip_atomic_load(ap, __ATOMIC_RELAXED,
                                       __HIP_MEMORY_SCOPE_AGENT);
            }
            zmbuf[fs * CH_ + lane] = val;
        }
        __syncthreads();                                   // B2

        if (comp) {
            // --- redundant per-wave LN stats, fixed order (identical bits
            //     in all waves and all 8 replica blocks of this batch) ---
            float s = 0.f, q2 = 0.f;
            #pragma unroll
            for (int k = 0; k < 8; ++k) {
                const float v = zmbuf[lane + 64 * k];   // bank-clean stride
                s += v; q2 += v * v;
            }
            #pragma unroll
            for (int m = 1; m < 64; m <<= 1) {
                s  += __shfl_xor(s, m);
                q2 += __shfl_xor(q2, m);
            }
            const float mu   = s * (1.0f / E_);
            const float var  = (q2 - s * mu) * (1.0f / (E_ - 1));
            const float invd = 1.0f / (sqrtf(var) + EPS_);
            const float zl   = gmm * (zmbuf[tid] - mu) * invd + btt;
            if (t == S_ - 1) {
                if (h == 0) zout[(size_t)b * E_ + tid] = zl;
            } else {
                zs[tid] = fmaf(e, sqrtE, zl);  // own row: next matvec reads
            }                                  // only this wave's rows
        }
    }
}

// ---------------------------------------------------------------------------
// K2: y = z @ W_voc + b_voc. 250 blocks x 512 threads; each thread owns one
// vocab column for 8 batches (bg group). z reads are thread-uniform ->
// scalar-cache loads; W_voc streamed once (same cols across bg reuse L1).
// ---------------------------------------------------------------------------
__global__ __launch_bounds__(512) void logits_k(
    const float* __restrict__ zfin,  // (B,E)
    const float* __restrict__ Wvoc,  // (E,V)
    const float* __restrict__ bvoc,  // (V)
    float* __restrict__ y)           // (B,V)
{
    const int tid = threadIdx.x;
    const int col = blockIdx.x * 128 + (tid & 127);
    const int bg  = (tid >> 7) * 8;           // 0,8,16,24

    float acc[8] = {0.f, 0.f, 0.f, 0.f, 0.f, 0.f, 0.f, 0.f};
    const float* wp = Wvoc + col;
    const float* zp = zfin + (size_t)bg * E_;

    for (int k = 0; k < E_; k += 4) {
        const float w0 = wp[(size_t)(k + 0) * V_];
        const float w1 = wp[(size_t)(k + 1) * V_];
        const float w2 = wp[(size_t)(k + 2) * V_];
        const float w3 = wp[(size_t)(k + 3) * V_];
        #pragma unroll
        for (int g = 0; g < 8; ++g) {
            acc[g] = fmaf(zp[g * E_ + k + 0], w0, acc[g]);
            acc[g] = fmaf(zp[g * E_ + k + 1], w1, acc[g]);
            acc[g] = fmaf(zp[g * E_ + k + 2], w2, acc[g]);
            acc[g] = fmaf(zp[g * E_ + k + 3], w3, acc[g]);
        }
    }
    const float bv = bvoc[col];
    #pragma unroll
    for (int g = 0; g < 8; ++g)
        y[(size_t)(bg + g) * V_ + col] = acc[g] + bv;
}

// ---------------------------------------------------------------------------
// K3: per-batch log-sum-exp (bias already folded into y)
// ---------------------------------------------------------------------------
__global__ __launch_bounds__(1024) void lse_k(
    const float* __restrict__ y, float* __restrict__ corr)
{
    __shared__ float redm[16], redl[16];
    const int b = blockIdx.x;
    const int tid = threadIdx.x;
    const float* row = y + (size_t)b * V_;

    float m = -3.0e38f, l = 0.f;
    for (int v = tid; v < V_; v += 1024) {
        const float x = row[v];
        const float nm = fmaxf(m, x);
        l = l * __expf(m - nm) + __expf(x - nm);
        m = nm;
    }
    #pragma unroll
    for (int off = 32; off > 0; off >>= 1) {
        const float om = __shfl_down(m, off);
        const float ol = __shfl_down(l, off);
        const float nm = fmaxf(m, om);
        l = l * __expf(m - nm) + ol * __expf(om - nm);
        m = nm;
    }
    const int lane = tid & 63, wvv = tid >> 6;
    if (lane == 0) { redm[wvv] = m; redl[wvv] = l; }
    __syncthreads();
    if (tid == 0) {
        float M = redm[0], L = redl[0];
        for (int k = 1; k < 16; ++k) {
            const float nm = fmaxf(M, redm[k]);
            L = L * __expf(M - nm) + redl[k] * __expf(redm[k] - nm);
            M = nm;
        }
        corr[b] = M + logf(L);
    }
}

// ---------------------------------------------------------------------------
// K4: y -= corr[b]
// ---------------------------------------------------------------------------
__global__ __launch_bounds__(256) void fix_k(
    float* __restrict__ y, const float* __restrict__ corr)
{
    const int idx = blockIdx.x * 256 + threadIdx.x;   // float4 index
    const size_t o = (size_t)idx * 4;
    const int b = (int)(o / V_);
    const float cr = corr[b];
    v4 v = *(v4*)(y + o);
    v = v - cr;
    *(v4*)(y + o) = v;
}

// ---------------------------------------------------------------------------
extern "C" void kernel_launch(void* const* d_in, const int* in_sizes, int n_in,
                              void* d_out, int out_size, void* d_ws, size_t ws_size,
                              hipStream_t stream)
{
    (void)in_sizes; (void)n_in; (void)out_size; (void)ws_size;
    // 0=hidden_state (unused), 1=output_sequence, 2=emb_out, 3=W_dec,
    // 4=b_dec, 5=gamma, 6=beta, 7=W_voc, 8=b_voc
    const int*   seq  = (const int*)  d_in[1];
    const float* emb  = (const float*)d_in[2];
    const float* Wdec = (const float*)d_in[3];
    const float* bdec = (const float*)d_in[4];
    const float* gam  = (const float*)d_in[5];
    const float* bet  = (const float*)d_in[6];
    const float* Wvoc = (const float*)d_in[7];
    const float* bvoc = (const float*)d_in[8];

    float* out  = (float*)d_out;
    float* zout = out;            // B*E floats
    float* y    = out + B_ * E_;  // B*V floats

    // workspace: values (B*2*E u64) + corr
    const size_t exch_u64 = (size_t)B_ * 2 * E_;
    u64*   zpub = (u64*)d_ws;
    float* corr = (float*)((char*)d_ws + exch_u64 * sizeof(u64)); // B floats

    // tags must not alias t+1 from a previous replay — zero the exchange buf
    hipMemsetAsync(zpub, 0, exch_u64 * sizeof(u64), stream);

    hipLaunchKernelGGL(scan2b, dim3(B_ * NH_), dim3(1024), 0, stream,
                       seq, emb, Wdec, bdec, gam, bet, zout, zpub);
    hipLaunchKernelGGL(logits_k, dim3(V_ / 128), dim3(512), 0, stream,
                       zout, Wvoc, bvoc, y);
    hipLaunchKernelGGL(lse_k, dim3(B_), dim3(1024), 0, stream, y, corr);
    hipLaunchKernelGGL(fix_k, dim3(1000), dim3(256), 0, stream, y, corr);
}